// Round 2
// baseline (465.499 us; speedup 1.0000x reference)
//
#include <hip/hip_runtime.h>

// EMA lta[t] = lta[t-1] + w*(x[t]-lta[t-1]), [B=256, T=60000, C=3] fp32.
//
// R3 (prev session): LDS-staged block scan, 321.4 us bench. R1 rocprof: kernel
// dispatch < 113.5 us (not in top-5; harness re-poison fills at 114 us / 6.4 TB/s
// own every slot). Kernel gap vs 60 us floor is serialization x residency:
// 3 tiles x ~4 syncs, 36 KB LDS -> 4 blocks/CU -> 2048 blocks in TWO rounds.
//
// R2 (this round): register-direct version, no LDS tile.
//  - each thread loads its own 12-step/144 B chunk: 9x global dwordx4 from one
//    base pointer + imm offsets. Lane stride 144 B; every 64 B line is fully
//    consumed by the same wave within the 9-load window -> no HBM over-fetch.
//  - pass2 re-loads the chunk (L1/L2 hit) instead of keeping it live -> VGPR
//    <= 64 -> __launch_bounds__(256, 8) -> 8 blocks/CU -> ALL 2048 blocks
//    resident in ONE round.
//  - exact (A,V) scan as before; wave totals double-buffered by tile parity ->
//    ONE __syncthreads per tile (3/block, was ~12). Carry computed redundantly
//    by all threads from the 4 wave totals (uniform broadcast) - no carry LDS.
//  - loads bounded at r1 exactly (old kernel staged past r1: ~29 MB wasted).
// Warm-up 512 steps at block starts unchanged (absmax 1.95e-3 vs 8.98e-3 thr).

#define T_LEN    60000
#define BATCH    256
#define CH       3
#define NBLK_ROW 8
#define SEG      7500        // T_LEN / NBLK_ROW, multiple of 4
#define WARM     512
#define LPT      12          // steps per thread per tile (multiple of 4)
#define TS       (256 * LPT) // 3072 steps per tile
#define NTILES   3           // ceil((SEG + WARM) / TS)

__global__ __launch_bounds__(256, 8) void lta_kernel(const float* __restrict__ x,
                                                     float* __restrict__ out) {
    __shared__ float wA[2][4], wV0[2][4], wV1[2][4], wV2[2][4];

    const int tid  = threadIdx.x;
    const int lane = tid & 63;
    const int wv   = tid >> 6;

    const int blk = blockIdx.x;
    const int b   = blk / NBLK_ROW;
    const int q   = blk % NBLK_ROW;

    const int r0 = q * SEG;                          // output start (mult of 4)
    const int r1 = r0 + SEG;                         // output end
    const int w0 = (r0 >= WARM) ? (r0 - WARM) : 0;   // scan start, carry=0 here

    const float w  = 0.015f;
    const float a  = 1.0f - w;                       // 0.985
    const float a4 = (a * a) * (a * a);

    const float* __restrict__ rowx = x   + (size_t)b * (T_LEN * CH);
    float* __restrict__       rowo = out + (size_t)b * (T_LEN * CH);

    float C0 = 0.f, C1 = 0.f, C2 = 0.f;              // running carry (uniform)

    for (int tix = 0; tix < NTILES; ++tix) {
        const int s0 = w0 + tix * TS;                // tile start (mult of 4)
        if (s0 >= r1) break;                         // block-uniform
        const int par = tix & 1;

        const int t_lo = s0 + LPT * tid;             // this thread's first step
        int Li = r1 - t_lo;                          // multiple of 4 by constr.
        Li = (Li < 0) ? 0 : (Li > LPT ? LPT : Li);
        const int ng = Li >> 2;                      // 0..3 groups of 4 steps

        // ---- pass 1: per-thread EMA from zero over its ng*4 steps ----
        // direct global loads: 9 dwordx4 off one base, imm offsets 0..128
        const float4* __restrict__ gp =
            (const float4*)(rowx + (size_t)t_lo * CH);
        float y0 = 0.f, y1 = 0.f, y2 = 0.f;
        for (int g = 0; g < ng; ++g) {
            float4 A4 = gp[3 * g + 0];
            float4 B4 = gp[3 * g + 1];
            float4 C4 = gp[3 * g + 2];
            y0 = fmaf(w, A4.x - y0, y0); y1 = fmaf(w, A4.y - y1, y1); y2 = fmaf(w, A4.z - y2, y2);
            y0 = fmaf(w, A4.w - y0, y0); y1 = fmaf(w, B4.x - y1, y1); y2 = fmaf(w, B4.y - y2, y2);
            y0 = fmaf(w, B4.z - y0, y0); y1 = fmaf(w, B4.w - y1, y1); y2 = fmaf(w, C4.x - y2, y2);
            y0 = fmaf(w, C4.y - y0, y0); y1 = fmaf(w, C4.z - y1, y1); y2 = fmaf(w, C4.w - y2, y2);
        }
        float AL = 1.0f;
        for (int g = 0; g < ng; ++g) AL *= a4;       // a^(4*ng)

        // ---- exact (A,V) scan: within-wave shuffles ----
        // segment transform y_out = A*y_in + V; compose R after L:
        //   (A,V) = (A_R*A_L, A_R*V_L + V_R)
        float As = AL, V0 = y0, V1 = y1, V2 = y2;    // inclusive accumulator
        #pragma unroll
        for (int d = 1; d < 64; d <<= 1) {
            float Au = __shfl_up(As, d, 64);
            float u0 = __shfl_up(V0, d, 64);
            float u1 = __shfl_up(V1, d, 64);
            float u2 = __shfl_up(V2, d, 64);
            if (lane >= d) {
                V0 = fmaf(As, u0, V0);
                V1 = fmaf(As, u1, V1);
                V2 = fmaf(As, u2, V2);
                As = As * Au;
            }
        }
        if (lane == 63) {
            wA[par][wv] = As; wV0[par][wv] = V0; wV1[par][wv] = V1; wV2[par][wv] = V2;
        }
        __syncthreads();                             // the ONLY sync this tile

        // exclusive within wave (shift inclusive by 1)
        float Ae = __shfl_up(As, 1, 64);
        float e0 = __shfl_up(V0, 1, 64);
        float e1 = __shfl_up(V1, 1, 64);
        float e2 = __shfl_up(V2, 1, 64);
        if (lane == 0) { Ae = 1.f; e0 = 0.f; e1 = 0.f; e2 = 0.f; }

        // prefix over earlier waves P = T_{wv-1} o ... o T_0, and block total
        float Ap = 1.f, p0 = 0.f, p1 = 0.f, p2 = 0.f;
        float At = 1.f, q0 = 0.f, q1 = 0.f, q2 = 0.f;
        #pragma unroll
        for (int k = 0; k < 4; ++k) {
            float Ak = wA[par][k];
            float k0 = wV0[par][k], k1 = wV1[par][k], k2 = wV2[par][k];
            if (k < wv) {                            // wave-uniform predicate
                p0 = fmaf(Ak, p0, k0);
                p1 = fmaf(Ak, p1, k1);
                p2 = fmaf(Ak, p2, k2);
                Ap *= Ak;
            }
            q0 = fmaf(Ak, q0, k0);
            q1 = fmaf(Ak, q1, k1);
            q2 = fmaf(Ak, q2, k2);
            At *= Ak;
        }

        // thread's true carry-in: Y = E o P applied to C (old C)
        const float Y0 = fmaf(Ae, fmaf(Ap, C0, p0), e0);
        const float Y1 = fmaf(Ae, fmaf(Ap, C1, p1), e1);
        const float Y2 = fmaf(Ae, fmaf(Ap, C2, p2), e2);

        // next tile's carry: block total applied to C (uniform on all threads)
        C0 = fmaf(At, C0, q0);
        C1 = fmaf(At, C1, q1);
        C2 = fmaf(At, C2, q2);

        // ---- pass 2: recompute from exact carry, store direct to global ----
        // skip threads entirely inside the warm-up region
        if (ng > 0 && (t_lo + 4 * ng) > r0) {
            float4* __restrict__ go = (float4*)(rowo + (size_t)t_lo * CH);
            const int fb = 3 * t_lo;                 // float index base (mult 4)
            const int f0 = 3 * r0;                   // store lower bound (mult 4)
            y0 = Y0; y1 = Y1; y2 = Y2;
            for (int g = 0; g < ng; ++g) {
                float4 A4 = gp[3 * g + 0];           // L1/L2 hit re-load
                float4 B4 = gp[3 * g + 1];
                float4 C4 = gp[3 * g + 2];
                float4 D, E, F;
                y0 = fmaf(w, A4.x - y0, y0);  D.x = y0;
                y1 = fmaf(w, A4.y - y1, y1);  D.y = y1;
                y2 = fmaf(w, A4.z - y2, y2);  D.z = y2;
                y0 = fmaf(w, A4.w - y0, y0);  D.w = y0;
                y1 = fmaf(w, B4.x - y1, y1);  E.x = y1;
                y2 = fmaf(w, B4.y - y2, y2);  E.y = y2;
                y0 = fmaf(w, B4.z - y0, y0);  E.z = y0;
                y1 = fmaf(w, B4.w - y1, y1);  E.w = y1;
                y2 = fmaf(w, C4.x - y2, y2);  F.x = y2;
                y0 = fmaf(w, C4.y - y0, y0);  F.y = y0;
                y1 = fmaf(w, C4.z - y1, y1);  F.z = y1;
                y2 = fmaf(w, C4.w - y2, y2);  F.w = y2;
                const int fg = fb + 12 * g;
                if (fg      >= f0) go[3 * g + 0] = D;
                if (fg + 4  >= f0) go[3 * g + 1] = E;
                if (fg + 8  >= f0) go[3 * g + 2] = F;
            }
        }
        // no trailing sync: wave-total scratch is parity double-buffered, and
        // tile i+2's re-write of parity p is separated from tile i's reads by
        // tile i+1's __syncthreads.
    }
}

extern "C" void kernel_launch(void* const* d_in, const int* in_sizes, int n_in,
                              void* d_out, int out_size, void* d_ws, size_t ws_size,
                              hipStream_t stream) {
    const float* x = (const float*)d_in[0];
    float* out = (float*)d_out;

    const int grid = BATCH * NBLK_ROW;   // 2048 blocks, 8/CU, single round
    lta_kernel<<<grid, 256, 0, stream>>>(x, out);
}

// Round 3
// 318.371 us; speedup vs baseline: 1.4621x; 1.4621x over previous
//
#include <hip/hip_runtime.h>

// EMA lta[t] = lta[t-1] + w*(x[t]-lta[t-1]), [B=256, T=60000, C=3] fp32.
//
// History:
//  R1 (LDS tile 36 KB, LPT=12): bench 321.4 us, kernel < 113.5 us. 4 blocks/CU,
//     2 dispatch rounds.
//  R2 (register-direct, no LDS): REGRESSED — kernel 241.7 us. Counters: FETCH
//     399 MB = 2.04x ideal (pass-2 re-loads missed L2: 9.2 MB/XCD working set
//     vs 4 MB L2), WRITE 418 MB = 2.27x ideal (16B/lane stores at 144B stride
//     fragment cache lines -> partial-line write-allocate). Lesson: the serial
//     recurrence forces contiguous per-thread time chunks; ONLY an LDS
//     transpose reconciles that with coalesced HBM access.
//  R3 (this round): R1 structure with residency fixes.
//     - LPT=4: tile 12 KB -> 8 blocks/CU (32 waves, HW max), 2048 blocks =
//       exactly ONE dispatch round (was 2).
//     - stage via __builtin_amdgcn_global_load_lds width=16 (no VGPR
//       round-trip); suffix-only predicate keeps lane 0 first-active, dest =
//       wave-uniform base + lane*16 (m97 pattern).
//     - stage bound clipped at r1 (R1 staged past r1: ~29 MB wasted fetch).
//     - R2's verified scan/carry algebra; parity-dbuf wave totals; redundant
//       block-total carry on all threads (no carry LDS, no tid==255 serial).
//     - chunk stride 12 dwords: gcd(12,32)=4 -> each ds_read_b128 8-lane group
//       covers all 32 banks once -> conflict-free.
// Warm-up 512 steps at block starts (0.985^512 = 4.4e-4 decay; absmax 1.95e-3
// vs 8.98e-3 threshold).

#define T_LEN    60000
#define BATCH    256
#define CH       3
#define NBLK_ROW 8
#define SEG      7500        // T_LEN / NBLK_ROW, multiple of 4
#define WARM     512
#define LPT      4           // steps per thread per tile
#define TS       (256 * LPT) // 1024 steps per tile
#define NTILES   8           // ceil((SEG + WARM) / TS)
#define TILE_F   (TS * CH)   // 3072 floats = 12 KB
#define F4PT     (LPT * CH / 4)  // 3 float4 per thread chunk

__global__ __launch_bounds__(256, 8) void lta_kernel(const float* __restrict__ x,
                                                     float* __restrict__ out) {
    __shared__ float tile[TILE_F];
    __shared__ float wA[2][4], wV0[2][4], wV1[2][4], wV2[2][4];

    const int tid  = threadIdx.x;
    const int lane = tid & 63;
    const int wv   = tid >> 6;

    const int blk = blockIdx.x;
    const int b   = blk / NBLK_ROW;
    const int q   = blk % NBLK_ROW;

    const int r0 = q * SEG;                          // output start (mult of 4)
    const int r1 = r0 + SEG;                         // output end
    const int w0 = (r0 >= WARM) ? (r0 - WARM) : 0;   // scan start, carry=0 here

    const float w  = 0.015f;
    const float a  = 1.0f - w;                       // 0.985
    const float a4 = (a * a) * (a * a);

    const float* __restrict__ rowx = x   + (size_t)b * (T_LEN * CH);
    float* __restrict__       rowo = out + (size_t)b * (T_LEN * CH);

    float C0 = 0.f, C1 = 0.f, C2 = 0.f;              // running carry (uniform)

    for (int tix = 0; tix < NTILES; ++tix) {
        const int s0 = w0 + tix * TS;                // tile start (mult of 4)
        if (s0 >= r1) break;                         // block-uniform
        const int par = tix & 1;

        // ---- stage: global -> LDS direct, coalesced 16B/lane ----
        const int valid_end = (s0 + TS < r1) ? (s0 + TS) : r1;
        const int bound_f4  = ((valid_end - s0) * CH) >> 2;
        {
            const float4* __restrict__ gx = (const float4*)(rowx + (size_t)s0 * CH);
            float4* lb = (float4*)tile;
            #pragma unroll
            for (int j = 0; j < F4PT; ++j) {         // 3
                const int f4 = j * 256 + tid;        // = wave-uniform base + lane
                if (f4 < bound_f4) {                 // suffix mask only
                    __builtin_amdgcn_global_load_lds(
                        (const __attribute__((address_space(1))) void*)(gx + f4),
                        (__attribute__((address_space(3))) void*)(lb + f4),
                        16, 0, 0);
                }
            }
        }
        __syncthreads();                             // sync 1: tile staged

        // ---- pass 1: per-thread EMA from zero over its <=4 steps ----
        const int t_lo = s0 + LPT * tid;
        int Li = r1 - t_lo;                          // multiple of 4 by constr.
        Li = (Li < 0) ? 0 : (Li > LPT ? LPT : Li);
        const int ng = Li >> 2;                      // 0 or 1

        const float4* __restrict__ lp = (const float4*)tile + tid * F4PT;
        float y0 = 0.f, y1 = 0.f, y2 = 0.f;
        float AL = 1.0f;
        if (ng) {
            float4 A4 = lp[0];
            float4 B4 = lp[1];
            float4 C4 = lp[2];
            y0 = fmaf(w, A4.x - y0, y0); y1 = fmaf(w, A4.y - y1, y1); y2 = fmaf(w, A4.z - y2, y2);
            y0 = fmaf(w, A4.w - y0, y0); y1 = fmaf(w, B4.x - y1, y1); y2 = fmaf(w, B4.y - y2, y2);
            y0 = fmaf(w, B4.z - y0, y0); y1 = fmaf(w, B4.w - y1, y1); y2 = fmaf(w, C4.x - y2, y2);
            y0 = fmaf(w, C4.y - y0, y0); y1 = fmaf(w, C4.z - y1, y1); y2 = fmaf(w, C4.w - y2, y2);
            AL = a4;
        }

        // ---- exact (A,V) scan across the wave ----
        // segment transform y_out = A*y_in + V; compose R after L:
        //   (A,V) = (A_R*A_L, A_R*V_L + V_R)
        float As = AL, V0 = y0, V1 = y1, V2 = y2;    // inclusive accumulator
        #pragma unroll
        for (int d = 1; d < 64; d <<= 1) {
            float Au = __shfl_up(As, d, 64);
            float u0 = __shfl_up(V0, d, 64);
            float u1 = __shfl_up(V1, d, 64);
            float u2 = __shfl_up(V2, d, 64);
            if (lane >= d) {
                V0 = fmaf(As, u0, V0);
                V1 = fmaf(As, u1, V1);
                V2 = fmaf(As, u2, V2);
                As = As * Au;
            }
        }
        if (lane == 63) {
            wA[par][wv] = As; wV0[par][wv] = V0; wV1[par][wv] = V1; wV2[par][wv] = V2;
        }
        __syncthreads();                             // sync 2: totals visible

        // exclusive within wave (shift inclusive by 1)
        float Ae = __shfl_up(As, 1, 64);
        float e0 = __shfl_up(V0, 1, 64);
        float e1 = __shfl_up(V1, 1, 64);
        float e2 = __shfl_up(V2, 1, 64);
        if (lane == 0) { Ae = 1.f; e0 = 0.f; e1 = 0.f; e2 = 0.f; }

        // prefix over earlier waves P = T_{wv-1} o ... o T_0, and block total
        float Ap = 1.f, p0 = 0.f, p1 = 0.f, p2 = 0.f;
        float At = 1.f, q0 = 0.f, q1 = 0.f, q2 = 0.f;
        #pragma unroll
        for (int k = 0; k < 4; ++k) {
            float Ak = wA[par][k];
            float k0 = wV0[par][k], k1 = wV1[par][k], k2 = wV2[par][k];
            if (k < wv) {                            // wave-uniform predicate
                p0 = fmaf(Ak, p0, k0);
                p1 = fmaf(Ak, p1, k1);
                p2 = fmaf(Ak, p2, k2);
                Ap *= Ak;
            }
            q0 = fmaf(Ak, q0, k0);
            q1 = fmaf(Ak, q1, k1);
            q2 = fmaf(Ak, q2, k2);
            At *= Ak;
        }

        // thread's true carry-in: Y = E o P applied to C (old C)
        const float Y0 = fmaf(Ae, fmaf(Ap, C0, p0), e0);
        const float Y1 = fmaf(Ae, fmaf(Ap, C1, p1), e1);
        const float Y2 = fmaf(Ae, fmaf(Ap, C2, p2), e2);

        // next tile's carry: block total applied to C (uniform on all threads)
        C0 = fmaf(At, C0, q0);
        C1 = fmaf(At, C1, q1);
        C2 = fmaf(At, C2, q2);

        // ---- pass 2: recompute from exact carry, write y over x in place ----
        // skip threads entirely inside the warm-up region (never stored)
        if (ng && (t_lo + LPT) > r0) {
            float4* __restrict__ lpw = (float4*)tile + tid * F4PT;
            float4 A4 = lpw[0];
            float4 B4 = lpw[1];
            float4 C4 = lpw[2];
            float4 D, E, F;
            y0 = Y0; y1 = Y1; y2 = Y2;
            y0 = fmaf(w, A4.x - y0, y0);  D.x = y0;
            y1 = fmaf(w, A4.y - y1, y1);  D.y = y1;
            y2 = fmaf(w, A4.z - y2, y2);  D.z = y2;
            y0 = fmaf(w, A4.w - y0, y0);  D.w = y0;
            y1 = fmaf(w, B4.x - y1, y1);  E.x = y1;
            y2 = fmaf(w, B4.y - y2, y2);  E.y = y2;
            y0 = fmaf(w, B4.z - y0, y0);  E.z = y0;
            y1 = fmaf(w, B4.w - y1, y1);  E.w = y1;
            y2 = fmaf(w, C4.x - y2, y2);  F.x = y2;
            y0 = fmaf(w, C4.y - y0, y0);  F.y = y0;
            y1 = fmaf(w, C4.z - y1, y1);  F.z = y1;
            y2 = fmaf(w, C4.w - y2, y2);  F.w = y2;
            lpw[0] = D;
            lpw[1] = E;
            lpw[2] = F;
        }
        __syncthreads();                             // sync 3: y visible

        // ---- coalesced float4 store of [max(s0,r0), min(s0+TS,r1)) ----
        {
            const int slo = (s0 > r0) ? s0 : r0;
            const int shi = (s0 + TS < r1) ? (s0 + TS) : r1;
            const int lo_f4 = ((slo - s0) * CH) >> 2;
            const int hi_f4 = ((shi - s0) * CH) >> 2;
            float4* __restrict__ go = (float4*)(rowo + (size_t)s0 * CH);
            const float4* __restrict__ lt = (const float4*)tile;
            #pragma unroll
            for (int j = 0; j < F4PT; ++j) {
                const int f4 = j * 256 + tid;
                if (f4 >= lo_f4 && f4 < hi_f4) go[f4] = lt[f4];
            }
        }
        __syncthreads();                             // sync 4: tile reusable
    }
}

extern "C" void kernel_launch(void* const* d_in, const int* in_sizes, int n_in,
                              void* d_out, int out_size, void* d_ws, size_t ws_size,
                              hipStream_t stream) {
    const float* x = (const float*)d_in[0];
    float* out = (float*)d_out;

    const int grid = BATCH * NBLK_ROW;   // 2048 blocks, 8/CU, single round
    lta_kernel<<<grid, 256, 0, stream>>>(x, out);
}